// Round 2
// baseline (43968.359 us; speedup 1.0000x reference)
//
#include <hip/hip_runtime.h>

// Problem dims
#define Lz   128
#define Hd   1024
#define Od   64
#define Sq   256
#define Bt   512
#define K1   2176   // h1(1024) | h2(1024) | z(128)
#define K2q  2048   // h1n(1024) | h2(1024)
#define G4H  4096
#define NBLK 272u

typedef __attribute__((ext_vector_type(8))) short  short8;
typedef __attribute__((ext_vector_type(4))) float  floatx4;

__device__ __forceinline__ short f2bf(float x) {
  unsigned u = __float_as_uint(x);
  unsigned r = (u + 0x7fffu + ((u >> 16) & 1u)) >> 16;
  return (short)r;
}
__device__ __forceinline__ float sigf(float x)   { return 1.0f / (1.0f + __expf(-x)); }
__device__ __forceinline__ float tanhf_(float x) { return 1.0f - 2.0f / (__expf(2.0f * x) + 1.0f); }

__device__ __forceinline__ void gl_lds(const short* g, void* l) {
  __builtin_amdgcn_global_load_lds(
      (__attribute__((address_space(1))) const void*)g,
      (__attribute__((address_space(3))) void*)l, 16, 0, 0);
}

// ---- manual grid barrier (sense/generation counter in ws) ----
__device__ __forceinline__ void gbar(unsigned* cnt, unsigned* gen) {
  __syncthreads();
  if (threadIdx.x == 0) {
    __threadfence();   // release: write back this block's global stores
    unsigned g = __hip_atomic_load(gen, __ATOMIC_RELAXED, __HIP_MEMORY_SCOPE_AGENT);
    unsigned a = __hip_atomic_fetch_add(cnt, 1u, __ATOMIC_ACQ_REL, __HIP_MEMORY_SCOPE_AGENT);
    if (a == NBLK - 1u) {
      __hip_atomic_store(cnt, 0u, __ATOMIC_RELAXED, __HIP_MEMORY_SCOPE_AGENT);
      __hip_atomic_store(gen, g + 1u, __ATOMIC_RELEASE, __HIP_MEMORY_SCOPE_AGENT);
    } else {
      while (__hip_atomic_load(gen, __ATOMIC_ACQUIRE, __HIP_MEMORY_SCOPE_AGENT) == g)
        __builtin_amdgcn_s_sleep(2);
    }
    __threadfence();   // acquire: invalidate caches before reading others' data
  }
  __syncthreads();
}

// ---- weight row reorder: block bn (0..63) holds 64 rows: gate g (ifgo), j (0..15)
__device__ __forceinline__ int oldrow(int nr) {
  int bn = nr >> 6, rem = nr & 63, g = rem >> 4, jj = rem & 15;
  return g * Hd + bn * 16 + jj;
}

struct Params {
  const short *W1r, *W2r, *Woutb;
  const float *b0v, *b1v, *bpro, *bout;
  short *A1_0, *A1_1, *A2_0, *A2_1;
  float *c1, *c2, *out;
  unsigned *bcnt, *bgen;
};

// ================= prep kernels =================
__global__ void k_conv_w1a(const float* __restrict__ Whh0, short* __restrict__ W1r) {
  int idx = blockIdx.x * 256 + threadIdx.x;        // 4096*1024
  int nr = idx >> 10, k = idx & 1023;
  W1r[nr * K1 + k] = f2bf(Whh0[oldrow(nr) * Hd + k]);
}
__global__ void k_conv_w1b(const float* __restrict__ Wih0, const float* __restrict__ Wout,
                           short* __restrict__ W1r) {
  int idx = blockIdx.x * 256 + threadIdx.x;        // 4096*1024  (W0out = Wih0p @ Wout)
  int nr = idx >> 10, c = idx & 1023;
  const float* wp = Wih0 + oldrow(nr) * (Lz + Od) + Lz;
  float acc = 0.f;
  #pragma unroll 8
  for (int q = 0; q < Od; ++q) acc += wp[q] * Wout[q * Hd + c];
  W1r[nr * K1 + Hd + c] = f2bf(acc);
}
__global__ void k_conv_w1c(const float* __restrict__ Wih0, short* __restrict__ W1r) {
  int idx = blockIdx.x * 256 + threadIdx.x;        // 4096*128
  int nr = idx >> 7, kz = idx & 127;
  W1r[nr * K1 + 2048 + kz] = f2bf(Wih0[oldrow(nr) * (Lz + Od) + kz]);
}
__global__ void k_conv_w2(const float* __restrict__ Wih1, const float* __restrict__ Whh1,
                          short* __restrict__ W2r) {
  int idx = blockIdx.x * 256 + threadIdx.x;        // 4096*2048
  int nr = idx >> 11, k = idx & 2047;
  int orow = oldrow(nr);
  float v = (k < Hd) ? Wih1[orow * Hd + k] : Whh1[orow * Hd + (k - Hd)];
  W2r[nr * K2q + k] = f2bf(v);
}
__global__ void k_conv_wout(const float* __restrict__ Wout, short* __restrict__ Woutb) {
  int idx = blockIdx.x * 256 + threadIdx.x;        // 64*1024
  Woutb[idx] = f2bf(Wout[idx]);
}
__global__ void k_vec(const float* __restrict__ bih0, const float* __restrict__ bhh0,
                      const float* __restrict__ bih1, const float* __restrict__ bhh1,
                      const float* __restrict__ Wih0, const float* __restrict__ bout,
                      float* __restrict__ b0v, float* __restrict__ b1v, float* __restrict__ bpro,
                      unsigned* __restrict__ bcnt, unsigned* __restrict__ bgen) {
  int n = blockIdx.x * 256 + threadIdx.x;          // 4096 (original gate order)
  if (n == 0) { *bcnt = 0u; *bgen = 0u; }          // zero barrier state every launch
  b0v[n] = bih0[n] + bhh0[n];
  b1v[n] = bih1[n] + bhh1[n];
  const float* wp = Wih0 + n * (Lz + Od) + Lz;
  float acc = 0.f;
  #pragma unroll 8
  for (int q = 0; q < Od; ++q) acc += wp[q] * bout[q];
  bpro[n] = acc;
}
__global__ void k_init(const float* __restrict__ z, const float* __restrict__ Wh,
                       const float* __restrict__ bh, const float* __restrict__ Wc,
                       const float* __restrict__ bc,
                       short* __restrict__ A1_0, short* __restrict__ A2_0,
                       float* __restrict__ c1, float* __restrict__ c2) {
  int idx = blockIdx.x * 256 + threadIdx.x;        // 512*1024
  int m = idx >> 10, n = idx & 1023;
  const float* zr = z + m * Lz;
  const float* whr = Wh + n * Lz;
  const float* wcr = Wc + n * Lz;
  float hh = bh[n], cc = bc[n];
  #pragma unroll 8
  for (int k = 0; k < Lz; ++k) { float zv = zr[k]; hh += zv * whr[k]; cc += zv * wcr[k]; }
  c1[idx] = cc;
  c2[idx] = cc;
  short hb = f2bf(hh);
  A1_0[m * K1 + n] = hb;            // h1(-1) = h0
  A1_0[m * K1 + Hd + n] = 0;        // h2 slot at t=0: no feedback
  A2_0[m * K2q + Hd + n] = hb;      // h2(-1) = h0 for layer-1 at t=0
}
__global__ void k_initz(const float* __restrict__ z, short* __restrict__ A1_0,
                        short* __restrict__ A1_1) {
  int idx = blockIdx.x * 256 + threadIdx.x;        // 512*128
  int m = idx >> 7, k = idx & 127;
  short v = f2bf(z[idx]);
  A1_0[m * K1 + 2048 + k] = v;
  A1_1[m * K1 + 2048 + k] = v;
}

// ================= main persistent kernel =================
#define MFMA16(a, b, c) __builtin_amdgcn_mfma_f32_16x16x32_bf16(a, b, c, 0, 0, 0)

__device__ __forceinline__ void gemm_win(
    const short* __restrict__ Asrc, int astride, int nk,
    const short* __restrict__ Wsrc,
    const float* __restrict__ bias, const float* __restrict__ bias2,
    float* __restrict__ cbuf,
    short* __restrict__ hd0, int hs0, int ho0,
    short* __restrict__ hd1, int hs1, int ho1,
    int m0, int bn, short* As, short* Ws, int tid)
{
  const int lane = tid & 63, w = tid >> 6;
  const int l15 = lane & 15, q = lane >> 4;
  const int srow = tid >> 3;                 // 0..31
  const int scol = (tid & 7) * 8;            // element column within 64-chunk
  const int wstride = nk * 64;               // W row length in elements
  floatx4 acc[2][4] = {};

  const short* Ab = Asrc + m0 * astride;
  const short* Wb = Wsrc + bn * 64 * wstride;
  char* AsB = (char*)As;
  char* WsB = (char*)Ws;

  for (int kk = 0; kk < nk; ++kk) {
    __syncthreads();
    const int kb = kk * 64;
    #pragma unroll
    for (int i = 0; i < 4; ++i)
      gl_lds(Ab + (srow + i * 32) * astride + kb + scol, AsB + w * 1024 + i * 4096);
    #pragma unroll
    for (int i = 0; i < 2; ++i)
      gl_lds(Wb + (srow + i * 32) * wstride + kb + scol, WsB + w * 1024 + i * 4096);
    asm volatile("s_waitcnt vmcnt(0)" ::: "memory");
    __syncthreads();
    #pragma unroll
    for (int ks = 0; ks < 2; ++ks) {
      short8 a0 = *(const short8*)(As + (w * 32 + l15) * 64 + ks * 32 + q * 8);
      short8 a1 = *(const short8*)(As + (w * 32 + 16 + l15) * 64 + ks * 32 + q * 8);
      short8 b0 = *(const short8*)(Ws + (l15) * 64 + ks * 32 + q * 8);
      short8 b1 = *(const short8*)(Ws + (16 + l15) * 64 + ks * 32 + q * 8);
      short8 b2 = *(const short8*)(Ws + (32 + l15) * 64 + ks * 32 + q * 8);
      short8 b3 = *(const short8*)(Ws + (48 + l15) * 64 + ks * 32 + q * 8);
      acc[0][0] = MFMA16(a0, b0, acc[0][0]);
      acc[0][1] = MFMA16(a0, b1, acc[0][1]);
      acc[0][2] = MFMA16(a0, b2, acc[0][2]);
      acc[0][3] = MFMA16(a0, b3, acc[0][3]);
      acc[1][0] = MFMA16(a1, b0, acc[1][0]);
      acc[1][1] = MFMA16(a1, b1, acc[1][1]);
      acc[1][2] = MFMA16(a1, b2, acc[1][2]);
      acc[1][3] = MFMA16(a1, b3, acc[1][3]);
    }
  }
  // fused LSTM cell epilogue: subtile s == gate s (i,f,g,o), same lane/reg alignment
  const int colh = bn * 16 + l15;
  #pragma unroll
  for (int ms = 0; ms < 2; ++ms) {
    #pragma unroll
    for (int r = 0; r < 4; ++r) {
      const int mg = m0 + w * 32 + ms * 16 + q * 4 + r;
      float iv = acc[ms][0][r] + bias[colh];
      float fv = acc[ms][1][r] + bias[Hd + colh];
      float gv = acc[ms][2][r] + bias[2 * Hd + colh];
      float ov = acc[ms][3][r] + bias[3 * Hd + colh];
      if (bias2) {
        iv += bias2[colh]; fv += bias2[Hd + colh];
        gv += bias2[2 * Hd + colh]; ov += bias2[3 * Hd + colh];
      }
      const int ci = mg * Hd + colh;
      float cn = sigf(fv) * cbuf[ci] + sigf(iv) * tanhf_(gv);
      cbuf[ci] = cn;
      float hn = sigf(ov) * tanhf_(cn);
      short hb = f2bf(hn);
      hd0[mg * hs0 + ho0 + colh] = hb;
      hd1[mg * hs1 + ho1 + colh] = hb;
    }
  }
}

__device__ __forceinline__ void out_win(const short* __restrict__ A1p,
    const short* __restrict__ Wo, const float* __restrict__ bout,
    float* __restrict__ out, int tt, int ob, int tid)
{
  const int lane = tid & 63, w = tid >> 6;
  const int l15 = lane & 15, q = lane >> 4;
  const int ms = w & 1, nh = w >> 1;
  const int m0 = ob * 32;
  floatx4 acc[2] = {};
  const short* Ar = A1p + (m0 + ms * 16 + l15) * K1 + Hd;   // h2 slot
  const short* B0 = Wo + (nh * 32 + l15) * Hd;
  for (int kk = 0; kk < Hd; kk += 32) {
    short8 a  = *(const short8*)(Ar + kk + q * 8);
    short8 b0 = *(const short8*)(B0 + kk + q * 8);
    short8 b1 = *(const short8*)(B0 + 16 * Hd + kk + q * 8);
    acc[0] = MFMA16(a, b0, acc[0]);
    acc[1] = MFMA16(a, b1, acc[1]);
  }
  #pragma unroll
  for (int s = 0; s < 2; ++s)
    #pragma unroll
    for (int r = 0; r < 4; ++r) {
      int m = m0 + ms * 16 + q * 4 + r;
      int n = nh * 32 + s * 16 + l15;
      out[m * (Sq * Od) + tt * Od + n] = acc[s][r] + bout[n];
    }
}

__global__ __launch_bounds__(256, 2) void lstm_main(Params p) {
  __shared__ __align__(16) short As[128 * 64];   // 16 KB
  __shared__ __align__(16) short Ws[64 * 64];    //  8 KB
  const int tid = threadIdx.x;
  const int blk = blockIdx.x;

  if (blk < 256) {
    // XCD-aware: 4 m-blocks sharing a weight tile land on the same XCD (heuristic)
    const int xcd = blk & 7, j = blk >> 3;
    const int bn = xcd * 8 + (j >> 2);   // 0..63
    const int mb = j & 3;                // 0..3
    const int m0 = mb * 128;
    for (int t = 0; t < Sq; ++t) {
      const int par = t & 1;
      const short* A1p = par ? p.A1_1 : p.A1_0;
      short* A1n = par ? p.A1_0 : p.A1_1;
      short* A2p = par ? p.A2_1 : p.A2_0;
      short* A2n = par ? p.A2_0 : p.A2_1;
      // window A: layer-0 gates (h1,h2,z folded) -> h1n, c1
      gemm_win(A1p, K1, 34, p.W1r, p.b0v, (t > 0) ? p.bpro : nullptr,
               p.c1, A1n, K1, 0, A2p, K2q, 0, m0, bn, As, Ws, tid);
      gbar(p.bcnt, p.bgen);
      // window B: layer-1 gates -> h2n, c2
      gemm_win(A2p, K2q, 32, p.W2r, p.b1v, nullptr,
               p.c2, A2n, K2q, Hd, A1n, K1, Hd, m0, bn, As, Ws, tid);
      gbar(p.bcnt, p.bgen);
    }
  } else {
    const int ob = blk - 256;   // 0..15
    for (int t = 0; t < Sq; ++t) {
      const short* A1p = (t & 1) ? p.A1_1 : p.A1_0;
      if (t > 0) out_win(A1p, p.Woutb, p.bout, p.out, t - 1, ob, tid);
      gbar(p.bcnt, p.bgen);
      gbar(p.bcnt, p.bgen);
    }
    out_win(p.A1_0, p.Woutb, p.bout, p.out, Sq - 1, ob, tid);  // h2(255) is in A1_0
  }
}

// ================= host =================
extern "C" void kernel_launch(void* const* d_in, const int* in_sizes, int n_in,
                              void* d_out, int out_size, void* d_ws, size_t ws_size,
                              hipStream_t stream) {
  const float* z    = (const float*)d_in[0];
  const float* Wh   = (const float*)d_in[1];
  const float* bh   = (const float*)d_in[2];
  const float* Wc   = (const float*)d_in[3];
  const float* bc   = (const float*)d_in[4];
  const float* Wih0 = (const float*)d_in[5];
  const float* Whh0 = (const float*)d_in[6];
  const float* bih0 = (const float*)d_in[7];
  const float* bhh0 = (const float*)d_in[8];
  const float* Wih1 = (const float*)d_in[9];
  const float* Whh1 = (const float*)d_in[10];
  const float* bih1 = (const float*)d_in[11];
  const float* bhh1 = (const float*)d_in[12];
  const float* Wout = (const float*)d_in[13];
  const float* bout = (const float*)d_in[14];
  float* out = (float*)d_out;

  char* ws = (char*)d_ws;
  size_t off = 0;
  auto carve = [&](size_t bytes) { char* p = ws + off; off = (off + bytes + 255) & ~size_t(255); return p; };
  short* W1r   = (short*)carve((size_t)G4H * K1 * 2);
  short* W2r   = (short*)carve((size_t)G4H * K2q * 2);
  short* Woutb = (short*)carve((size_t)Od * Hd * 2);
  float* b0v   = (float*)carve(G4H * 4);
  float* b1v   = (float*)carve(G4H * 4);
  float* bpro  = (float*)carve(G4H * 4);
  short* A1_0  = (short*)carve((size_t)Bt * K1 * 2);
  short* A1_1  = (short*)carve((size_t)Bt * K1 * 2);
  short* A2_0  = (short*)carve((size_t)Bt * K2q * 2);
  short* A2_1  = (short*)carve((size_t)Bt * K2q * 2);
  float* c1    = (float*)carve((size_t)Bt * Hd * 4);
  float* c2    = (float*)carve((size_t)Bt * Hd * 4);
  unsigned* bar = (unsigned*)carve(256);

  k_conv_w1a<<<16384, 256, 0, stream>>>(Whh0, W1r);
  k_conv_w1b<<<16384, 256, 0, stream>>>(Wih0, Wout, W1r);
  k_conv_w1c<<<2048, 256, 0, stream>>>(Wih0, W1r);
  k_conv_w2 <<<32768, 256, 0, stream>>>(Wih1, Whh1, W2r);
  k_conv_wout<<<256, 256, 0, stream>>>(Wout, Woutb);
  k_vec<<<16, 256, 0, stream>>>(bih0, bhh0, bih1, bhh1, Wih0, bout, b0v, b1v, bpro,
                                bar, bar + 1);
  k_init<<<2048, 256, 0, stream>>>(z, Wh, bh, Wc, bc, A1_0, A2_0, c1, c2);
  k_initz<<<256, 256, 0, stream>>>(z, A1_0, A1_1);

  Params pr{W1r, W2r, Woutb, b0v, b1v, bpro, bout,
            A1_0, A1_1, A2_0, A2_1, c1, c2, out, bar, bar + 1};
  lstm_main<<<dim3(NBLK), dim3(256), 0, stream>>>(pr);
}

// Round 3
// 35524.207 us; speedup vs baseline: 1.2377x; 1.2377x over previous
//
#include <hip/hip_runtime.h>

// Problem dims
#define Lz   128
#define Hd   1024
#define Od   64
#define Sq   256
#define Bt   512
#define K1   2176   // h1(1024) | h2(1024) | z(128)
#define K2q  2048   // h1n(1024) | h2(1024)
#define G4H  4096
#define NBLK 528u   // 512 GEMM (8 mb x 64 bn, 64x64 tiles) + 16 out

typedef __attribute__((ext_vector_type(8))) short  short8;
typedef __attribute__((ext_vector_type(4))) float  floatx4;

__device__ __forceinline__ short f2bf(float x) {
  unsigned u = __float_as_uint(x);
  unsigned r = (u + 0x7fffu + ((u >> 16) & 1u)) >> 16;
  return (short)r;
}
__device__ __forceinline__ float sigf(float x)   { return 1.0f / (1.0f + __expf(-x)); }
__device__ __forceinline__ float tanhf_(float x) { return 1.0f - 2.0f / (__expf(2.0f * x) + 1.0f); }

__device__ __forceinline__ void gl_lds(const short* g, void* l) {
  __builtin_amdgcn_global_load_lds(
      (__attribute__((address_space(1))) const void*)g,
      (__attribute__((address_space(3))) void*)l, 16, 0, 0);
}

// ---- grid barrier: 1 release-add per block, relaxed polls, 1 acquire fence ----
__device__ __forceinline__ void gbar(unsigned* cnt, unsigned* gen) {
  __syncthreads();
  if (threadIdx.x == 0) {
    unsigned g = __hip_atomic_load(gen, __ATOMIC_RELAXED, __HIP_MEMORY_SCOPE_AGENT);
    unsigned a = __hip_atomic_fetch_add(cnt, 1u, __ATOMIC_RELEASE, __HIP_MEMORY_SCOPE_AGENT);
    if (a == NBLK - 1u) {
      __builtin_amdgcn_fence(__ATOMIC_ACQUIRE, "agent");
      __hip_atomic_store(cnt, 0u, __ATOMIC_RELAXED, __HIP_MEMORY_SCOPE_AGENT);
      __hip_atomic_store(gen, g + 1u, __ATOMIC_RELEASE, __HIP_MEMORY_SCOPE_AGENT);
    } else {
      for (;;) {
        bool done = false;
        for (int i = 0; i < 16; ++i) {
          if (__hip_atomic_load(gen, __ATOMIC_RELAXED, __HIP_MEMORY_SCOPE_AGENT) != g) { done = true; break; }
          __builtin_amdgcn_s_sleep(2);
        }
        if (done) break;
        if (__hip_atomic_load(gen, __ATOMIC_ACQUIRE, __HIP_MEMORY_SCOPE_AGENT) != g) break;
      }
      __builtin_amdgcn_fence(__ATOMIC_ACQUIRE, "agent");
    }
  }
  __syncthreads();
}

// ---- weight row reorder: block bn (0..63) holds 64 rows: gate g (ifgo), j (0..15)
__device__ __forceinline__ int oldrow(int nr) {
  int bn = nr >> 6, rem = nr & 63, g = rem >> 4, jj = rem & 15;
  return g * Hd + bn * 16 + jj;
}

struct Params {
  const short *W1r, *W2r, *Woutb;
  const float *b0v, *b1v, *bpro, *bout;
  short *A1_0, *A1_1, *A2_0, *A2_1;
  float *c1, *c2, *out;
  unsigned *bcnt, *bgen;
};

// ================= prep kernels =================
__global__ void k_conv_w1a(const float* __restrict__ Whh0, short* __restrict__ W1r) {
  int idx = blockIdx.x * 256 + threadIdx.x;        // 4096*1024
  int nr = idx >> 10, k = idx & 1023;
  W1r[nr * K1 + k] = f2bf(Whh0[oldrow(nr) * Hd + k]);
}
__global__ void k_conv_w1b(const float* __restrict__ Wih0, const float* __restrict__ Wout,
                           short* __restrict__ W1r) {
  int idx = blockIdx.x * 256 + threadIdx.x;        // 4096*1024  (W0out = Wih0p @ Wout)
  int nr = idx >> 10, c = idx & 1023;
  const float* wp = Wih0 + oldrow(nr) * (Lz + Od) + Lz;
  float acc = 0.f;
  #pragma unroll 8
  for (int q = 0; q < Od; ++q) acc += wp[q] * Wout[q * Hd + c];
  W1r[nr * K1 + Hd + c] = f2bf(acc);
}
__global__ void k_conv_w1c(const float* __restrict__ Wih0, short* __restrict__ W1r) {
  int idx = blockIdx.x * 256 + threadIdx.x;        // 4096*128
  int nr = idx >> 7, kz = idx & 127;
  W1r[nr * K1 + 2048 + kz] = f2bf(Wih0[oldrow(nr) * (Lz + Od) + kz]);
}
__global__ void k_conv_w2(const float* __restrict__ Wih1, const float* __restrict__ Whh1,
                          short* __restrict__ W2r) {
  int idx = blockIdx.x * 256 + threadIdx.x;        // 4096*2048
  int nr = idx >> 11, k = idx & 2047;
  int orow = oldrow(nr);
  float v = (k < Hd) ? Wih1[orow * Hd + k] : Whh1[orow * Hd + (k - Hd)];
  W2r[nr * K2q + k] = f2bf(v);
}
__global__ void k_conv_wout(const float* __restrict__ Wout, short* __restrict__ Woutb) {
  int idx = blockIdx.x * 256 + threadIdx.x;        // 64*1024
  Woutb[idx] = f2bf(Wout[idx]);
}
__global__ void k_vec(const float* __restrict__ bih0, const float* __restrict__ bhh0,
                      const float* __restrict__ bih1, const float* __restrict__ bhh1,
                      const float* __restrict__ Wih0, const float* __restrict__ bout,
                      float* __restrict__ b0v, float* __restrict__ b1v, float* __restrict__ bpro,
                      unsigned* __restrict__ bcnt, unsigned* __restrict__ bgen) {
  int n = blockIdx.x * 256 + threadIdx.x;          // 4096 (original gate order)
  if (n == 0) { *bcnt = 0u; *bgen = 0u; }          // zero barrier state every launch
  b0v[n] = bih0[n] + bhh0[n];
  b1v[n] = bih1[n] + bhh1[n];
  const float* wp = Wih0 + n * (Lz + Od) + Lz;
  float acc = 0.f;
  #pragma unroll 8
  for (int q = 0; q < Od; ++q) acc += wp[q] * bout[q];
  bpro[n] = acc;
}
__global__ void k_init(const float* __restrict__ z, const float* __restrict__ Wh,
                       const float* __restrict__ bh, const float* __restrict__ Wc,
                       const float* __restrict__ bc,
                       short* __restrict__ A1_0, short* __restrict__ A2_0,
                       float* __restrict__ c1, float* __restrict__ c2) {
  int idx = blockIdx.x * 256 + threadIdx.x;        // 512*1024
  int m = idx >> 10, n = idx & 1023;
  const float* zr = z + m * Lz;
  const float* whr = Wh + n * Lz;
  const float* wcr = Wc + n * Lz;
  float hh = bh[n], cc = bc[n];
  #pragma unroll 8
  for (int k = 0; k < Lz; ++k) { float zv = zr[k]; hh += zv * whr[k]; cc += zv * wcr[k]; }
  c1[idx] = cc;
  c2[idx] = cc;
  short hb = f2bf(hh);
  A1_0[m * K1 + n] = hb;            // h1(-1) = h0
  A1_0[m * K1 + Hd + n] = 0;        // h2 slot at t=0: no feedback
  A2_0[m * K2q + Hd + n] = hb;      // h2(-1) = h0 for layer-1 at t=0
}
__global__ void k_initz(const float* __restrict__ z, short* __restrict__ A1_0,
                        short* __restrict__ A1_1) {
  int idx = blockIdx.x * 256 + threadIdx.x;        // 512*128
  int m = idx >> 7, k = idx & 127;
  short v = f2bf(z[idx]);
  A1_0[m * K1 + 2048 + k] = v;
  A1_1[m * K1 + 2048 + k] = v;
}

// ================= main persistent kernel =================
#define MFMA16(a, b, c) __builtin_amdgcn_mfma_f32_16x16x32_bf16(a, b, c, 0, 0, 0)

// 64x64 tile: 4 waves, wave w = m-rows [w*16, w*16+16), n-subtiles 0..3 = gates i,f,g,o.
// LDS XOR swizzle: 16B chunk cc of row r lives at chunk slot (cc ^ (r&7)) within the row,
// compatible with gl_lds's "uniform base + lane*16" DMA placement.
__device__ __forceinline__ void gemm_win(
    const short* __restrict__ Asrc, int astride, int nk,
    const short* __restrict__ Wsrc,
    const float* __restrict__ bz,     // 4 gate biases (regs)
    float* __restrict__ cr,           // 4 cell-state regs
    short* __restrict__ hd0, int hs0, int ho0,
    short* __restrict__ hd1, int hs1, int ho1,
    int m0, int bn, short* As, short* Ws, int tid)
{
  const int lane = tid & 63, w = tid >> 6;
  const int l15 = lane & 15, q = lane >> 4;
  const int wstride = nk * 64;
  floatx4 acc[4] = {};

  const short* Ab = Asrc + m0 * astride;
  const short* Wb = Wsrc + bn * 64 * wstride;

  // stage chunk kk into buffer half b: 2 gl_lds for A (64x64), 2 for W (64x64)
  auto stage = [&](int kk, int b) {
    const int kb = kk * 64;
    short* as = As + b * 4096;
    short* ws = Ws + b * 4096;
    #pragma unroll
    for (int i = 0; i < 2; ++i) {
      int s = i * 256 + tid;
      int row = s >> 3;
      int cg = (tid & 7) ^ (row & 7);
      gl_lds(Ab + row * astride + kb + cg * 8, as + s * 8);
      gl_lds(Wb + row * wstride + kb + cg * 8, ws + s * 8);
    }
  };

  stage(0, 0);
  for (int kk = 0; kk < nk; ++kk) {
    asm volatile("s_waitcnt vmcnt(0)" ::: "memory");
    __syncthreads();
    if (kk + 1 < nk) stage(kk + 1, (kk + 1) & 1);
    const short* as = As + (kk & 1) * 4096;
    const short* ws = Ws + (kk & 1) * 4096;
    #pragma unroll
    for (int ks = 0; ks < 2; ++ks) {
      const int ar = w * 16 + l15;
      short8 a = *(const short8*)(as + ar * 64 + (((ks * 4 + q) ^ (ar & 7)) * 8));
      #pragma unroll
      for (int ns = 0; ns < 4; ++ns) {
        const int br = ns * 16 + l15;
        short8 b = *(const short8*)(ws + br * 64 + (((ks * 4 + q) ^ (br & 7)) * 8));
        acc[ns] = MFMA16(a, b, acc[ns]);
      }
    }
  }
  // fused LSTM cell epilogue (gates register-local; c in registers)
  const int colh = bn * 16 + l15;
  #pragma unroll
  for (int r = 0; r < 4; ++r) {
    const int mg = m0 + w * 16 + q * 4 + r;
    float iv = acc[0][r] + bz[0];
    float fv = acc[1][r] + bz[1];
    float gv = acc[2][r] + bz[2];
    float ov = acc[3][r] + bz[3];
    float cn = sigf(fv) * cr[r] + sigf(iv) * tanhf_(gv);
    cr[r] = cn;
    short hb = f2bf(sigf(ov) * tanhf_(cn));
    hd0[mg * hs0 + ho0 + colh] = hb;
    hd1[mg * hs1 + ho1 + colh] = hb;
  }
}

__device__ __forceinline__ void out_win(const short* __restrict__ A1p,
    const short* __restrict__ Wo, const float* __restrict__ bout,
    float* __restrict__ out, int tt, int ob, int tid)
{
  const int lane = tid & 63, w = tid >> 6;
  const int l15 = lane & 15, q = lane >> 4;
  const int ms = w & 1, nh = w >> 1;
  const int m0 = ob * 32;
  floatx4 acc[2] = {};
  const short* Ar = A1p + (m0 + ms * 16 + l15) * K1 + Hd;   // h2 slot
  const short* B0 = Wo + (nh * 32 + l15) * Hd;
  for (int kk = 0; kk < Hd; kk += 32) {
    short8 a  = *(const short8*)(Ar + kk + q * 8);
    short8 b0 = *(const short8*)(B0 + kk + q * 8);
    short8 b1 = *(const short8*)(B0 + 16 * Hd + kk + q * 8);
    acc[0] = MFMA16(a, b0, acc[0]);
    acc[1] = MFMA16(a, b1, acc[1]);
  }
  #pragma unroll
  for (int s = 0; s < 2; ++s)
    #pragma unroll
    for (int r = 0; r < 4; ++r) {
      int m = m0 + ms * 16 + q * 4 + r;
      int n = nh * 32 + s * 16 + l15;
      out[m * (Sq * Od) + tt * Od + n] = acc[s][r] + bout[n];
    }
}

__global__ __launch_bounds__(256, 3) void lstm_main(Params p) {
  __shared__ __align__(16) short As[2 * 64 * 64];   // 16 KB (double-buffered)
  __shared__ __align__(16) short Ws[2 * 64 * 64];   // 16 KB
  const int tid = threadIdx.x;
  const int blk = blockIdx.x;

  if (blk < 512) {
    // XCD-aware: the 8 mb-blocks sharing a bn weight slice land on one XCD (heuristic)
    const int xcd = blk & 7, j = blk >> 3;
    const int bn = xcd * 8 + (j >> 3);   // 0..63
    const int m0 = (j & 7) * 64;         // mb 0..7
    const int lane = tid & 63, w = tid >> 6;
    const int l15 = lane & 15, q = lane >> 4;
    const int colh = bn * 16 + l15;

    // biases and cell state live in registers for the whole sequence
    float bA[4], bAP[4], bB[4], c1r[4], c2r[4];
    #pragma unroll
    for (int g = 0; g < 4; ++g) {
      bA[g]  = p.b0v[g * Hd + colh];
      bAP[g] = bA[g] + p.bpro[g * Hd + colh];
      bB[g]  = p.b1v[g * Hd + colh];
    }
    #pragma unroll
    for (int r = 0; r < 4; ++r) {
      const int mg = m0 + w * 16 + q * 4 + r;
      c1r[r] = p.c1[mg * Hd + colh];
      c2r[r] = p.c2[mg * Hd + colh];
    }

    for (int t = 0; t < Sq; ++t) {
      const int par = t & 1;
      const short* A1p = par ? p.A1_1 : p.A1_0;
      short* A1n = par ? p.A1_0 : p.A1_1;
      short* A2p = par ? p.A2_1 : p.A2_0;
      short* A2n = par ? p.A2_0 : p.A2_1;
      // window A: layer-0 gates (h1,h2,z folded) -> h1n, c1
      gemm_win(A1p, K1, 34, p.W1r, (t > 0) ? bAP : bA, c1r,
               A1n, K1, 0, A2p, K2q, 0, m0, bn, As, Ws, tid);
      gbar(p.bcnt, p.bgen);
      // window B: layer-1 gates -> h2n, c2
      gemm_win(A2p, K2q, 32, p.W2r, bB, c2r,
               A2n, K2q, Hd, A1n, K1, Hd, m0, bn, As, Ws, tid);
      gbar(p.bcnt, p.bgen);
    }
  } else {
    const int ob = blk - 512;   // 0..15
    for (int t = 0; t < Sq; ++t) {
      const short* A1p = (t & 1) ? p.A1_1 : p.A1_0;
      if (t > 0) out_win(A1p, p.Woutb, p.bout, p.out, t - 1, ob, tid);
      gbar(p.bcnt, p.bgen);
      gbar(p.bcnt, p.bgen);
    }
    out_win(p.A1_0, p.Woutb, p.bout, p.out, Sq - 1, ob, tid);  // h2(255) is in A1_0
  }
}

// ================= host =================
extern "C" void kernel_launch(void* const* d_in, const int* in_sizes, int n_in,
                              void* d_out, int out_size, void* d_ws, size_t ws_size,
                              hipStream_t stream) {
  const float* z    = (const float*)d_in[0];
  const float* Wh   = (const float*)d_in[1];
  const float* bh   = (const float*)d_in[2];
  const float* Wc   = (const float*)d_in[3];
  const float* bc   = (const float*)d_in[4];
  const float* Wih0 = (const float*)d_in[5];
  const float* Whh0 = (const float*)d_in[6];
  const float* bih0 = (const float*)d_in[7];
  const float* bhh0 = (const float*)d_in[8];
  const float* Wih1 = (const float*)d_in[9];
  const float* Whh1 = (const float*)d_in[10];
  const float* bih1 = (const float*)d_in[11];
  const float* bhh1 = (const float*)d_in[12];
  const float* Wout = (const float*)d_in[13];
  const float* bout = (const float*)d_in[14];
  float* out = (float*)d_out;

  char* ws = (char*)d_ws;
  size_t off = 0;
  auto carve = [&](size_t bytes) { char* p = ws + off; off = (off + bytes + 255) & ~size_t(255); return p; };
  short* W1r   = (short*)carve((size_t)G4H * K1 * 2);
  short* W2r   = (short*)carve((size_t)G4H * K2q * 2);
  short* Woutb = (short*)carve((size_t)Od * Hd * 2);
  float* b0v   = (float*)carve(G4H * 4);
  float* b1v   = (float*)carve(G4H * 4);
  float* bpro  = (float*)carve(G4H * 4);
  short* A1_0  = (short*)carve((size_t)Bt * K1 * 2);
  short* A1_1  = (short*)carve((size_t)Bt * K1 * 2);
  short* A2_0  = (short*)carve((size_t)Bt * K2q * 2);
  short* A2_1  = (short*)carve((size_t)Bt * K2q * 2);
  float* c1    = (float*)carve((size_t)Bt * Hd * 4);
  float* c2    = (float*)carve((size_t)Bt * Hd * 4);
  unsigned* bar = (unsigned*)carve(256);

  k_conv_w1a<<<16384, 256, 0, stream>>>(Whh0, W1r);
  k_conv_w1b<<<16384, 256, 0, stream>>>(Wih0, Wout, W1r);
  k_conv_w1c<<<2048, 256, 0, stream>>>(Wih0, W1r);
  k_conv_w2 <<<32768, 256, 0, stream>>>(Wih1, Whh1, W2r);
  k_conv_wout<<<256, 256, 0, stream>>>(Wout, Woutb);
  k_vec<<<16, 256, 0, stream>>>(bih0, bhh0, bih1, bhh1, Wih0, bout, b0v, b1v, bpro,
                                bar, bar + 1);
  k_init<<<2048, 256, 0, stream>>>(z, Wh, bh, Wc, bc, A1_0, A2_0, c1, c2);
  k_initz<<<256, 256, 0, stream>>>(z, A1_0, A1_1);

  Params pr{W1r, W2r, Woutb, b0v, b1v, bpro, bout,
            A1_0, A1_1, A2_0, A2_1, c1, c2, out, bar, bar + 1};
  lstm_main<<<dim3(NBLK), dim3(256), 0, stream>>>(pr);
}